// Round 6
// baseline (415.209 us; speedup 1.0000x reference)
//
#include <hip/hip_runtime.h>
#include <hip/hip_bf16.h>
#include <math.h>

#define B_SZ    4
#define S_LEN   4096
#define DMODEL  1024
#define NH      16
#define KDIM    64
#define NF      256
#define NROWS   (B_SZ * S_LEN)          // 16384
#define NCHUNK  8                       // kv partial chunks (512 rows each)
#define RFF_SCALE 0.08838834764831845f  // sqrt(2/256)
#define NORM_Q    0.125f                // 1/sqrt(64)

typedef __attribute__((ext_vector_type(8))) short s8v;
typedef __attribute__((ext_vector_type(4))) float f4v;

static __device__ __forceinline__ unsigned short f2bf(float f) {
  unsigned u = __float_as_uint(f);
  unsigned r = (u + 0x7FFFu + ((u >> 16) & 1u)) >> 16;   // RNE
  return (unsigned short)r;
}

#define MFMA16(a, b, c) __builtin_amdgcn_mfma_f32_16x16x32_bf16((a), (b), (c), 0, 0, 0)

// async global->LDS, 16B per lane. LDS dest is wave-uniform base + lane*16.
__device__ __forceinline__ void glds16(const void* g, void* l) {
  __builtin_amdgcn_global_load_lds(
      (const __attribute__((address_space(1))) void*)g,
      (__attribute__((address_space(3))) void*)l, 16, 0, 0);
}

// ---------------------------------------------------------------------------
// cast x fp32 -> bf16
// ---------------------------------------------------------------------------
__global__ __launch_bounds__(256) void cast_bf16_kernel(
    const float* __restrict__ src, unsigned short* __restrict__ dst, int n8)
{
  int i = blockIdx.x * 256 + threadIdx.x;
  if (i >= n8) return;
  const float* s = src + (size_t)i * 8;
  float4 a = *(const float4*)s;
  float4 b = *(const float4*)(s + 4);
  union { s8v v; unsigned short u[8]; } o;
  o.u[0]=f2bf(a.x); o.u[1]=f2bf(a.y); o.u[2]=f2bf(a.z); o.u[3]=f2bf(a.w);
  o.u[4]=f2bf(b.x); o.u[5]=f2bf(b.y); o.u[6]=f2bf(b.z); o.u[7]=f2bf(b.w);
  *(s8v*)(dst + (size_t)i * 8) = o.v;
}

// ---------------------------------------------------------------------------
// transpose+cast: W[1024][1024] fp32 -> WT[1024][1024] bf16
// ---------------------------------------------------------------------------
__global__ __launch_bounds__(256) void transpose_cast_kernel(
    const float* __restrict__ W, unsigned short* __restrict__ WT)
{
  __shared__ float t[32][33];
  const int k0 = blockIdx.y * 32, n0 = blockIdx.x * 32;
  const int c = threadIdx.x & 31, r4 = threadIdx.x >> 5;
#pragma unroll
  for (int i = 0; i < 4; ++i) {
    int row = r4 + i * 8;
    t[row][c] = W[(size_t)(k0 + row) * 1024 + n0 + c];
  }
  __syncthreads();
#pragma unroll
  for (int i = 0; i < 4; ++i) {
    int row = r4 + i * 8;
    WT[(size_t)(n0 + row) * 1024 + k0 + c] = f2bf(t[c][row]);
  }
}

// rffW[64][256] fp32 -> rffWT[256][64] bf16, NORM folded in
__global__ __launch_bounds__(256) void prep_rff_kernel(
    const float* __restrict__ rffW, unsigned short* __restrict__ rffWT)
{
  int i = blockIdx.x * 256 + threadIdx.x;   // 16384
  int f = i >> 6, d = i & 63;
  rffWT[(size_t)f * 64 + d] = f2bf(rffW[(size_t)d * 256 + f] * NORM_Q);
}

// ---------------------------------------------------------------------------
// bf16 MFMA GEMM, 256x256 tile / BK=64 / 8 waves / 8-phase schedule.
// ROUND-1 VERSION VERBATIM (best measured: 115 us QKV, 0 bank conflicts).
// ---------------------------------------------------------------------------
template <int OUT_BF16, int QKV_FUSED>
__global__ __launch_bounds__(512, 2) void gemm_bt_kernel(
    const unsigned short* __restrict__ A,
    const unsigned short* __restrict__ BT0,
    const unsigned short* __restrict__ BT1,
    const unsigned short* __restrict__ BT2,
    const float* __restrict__ bias0, const float* __restrict__ bias1,
    const float* __restrict__ bias2,
    void* __restrict__ out0, void* __restrict__ out1, void* __restrict__ out2,
    int M, int N, int K, int NXT)
{
  __shared__ __align__(16) unsigned short As[2][16384];   // 64 KiB
  __shared__ __align__(16) unsigned short Bs[2][16384];   // 64 KiB
  const int tid = threadIdx.x;
  const int lane = tid & 63, wave = tid >> 6;

  // bijective XCD-aware swizzle on flattened workgroup id (m204)
  int wg = blockIdx.x;
  {
    const int nwg = gridDim.x;
    const int q = nwg >> 3, r = nwg & 7;
    const int xcd = wg & 7, pos = wg >> 3;
    wg = (xcd < r ? xcd * (q + 1) : r * (q + 1) + (xcd - r) * q) + pos;
  }
  const int m0 = (wg / NXT) * 256;
  int ngl = (wg % NXT) * 256;
  const unsigned short* BT = BT0;
  const float* bias = bias0;
  void* outp = out0;
  if (QKV_FUSED) {
    int which = ngl >> 10;
    if (which == 1) { BT = BT1; bias = bias1; outp = out1; }
    else if (which == 2) { BT = BT2; bias = bias2; outp = out2; }
    ngl &= 1023;
  }
  const int n0 = ngl;

  // staging addressing: thread covers LDS row trow, 16B chunk (lane&7).
  const int trow = tid >> 3;                       // 0..63
  const int g8 = (((lane & 7) ^ (trow & 7)) * 8);  // swizzled col (elements)
  const unsigned short* aPtr = A  + (size_t)(m0 + trow) * K + g8;
  const unsigned short* bPtr = BT + (size_t)(n0 + trow) * K + g8;
  const int NT = K >> 6;

  auto STAGE = [&](int ts, int h) {   // h: 0=A0 1=B0 2=A1 3=B1
    if (ts >= NT) return;
    const int buf = ts & 1, half = h >> 1;
    const size_t go = (size_t)half * 128 * K + (size_t)ts * 64;
    if ((h & 1) == 0) {
      unsigned short* lp = &As[buf][half * 8192 + wave * 512];
      glds16(aPtr + go, lp);
      glds16(aPtr + go + (size_t)64 * K, lp + 4096);
    } else {
      unsigned short* lp = &Bs[buf][half * 8192 + wave * 512];
      glds16(bPtr + go, lp);
      glds16(bPtr + go + (size_t)64 * K, lp + 4096);
    }
  };

  // fragment read addressing (swizzled: chunk ^= row&7; row&7 == col&7)
  const int col = lane & 15, quad = lane >> 4;
  const int wm = (wave >> 2) * 128;   // wave row base (2 row-waves)
  const int wn = (wave & 3) * 64;     // wave col base (4 col-waves)
  const int c7 = col & 7;
  const int idxA0 = (wm + col) * 64 + ((quad ^ c7) * 8);        // kk=0
  const int idxA1 = (wm + col) * 64 + (((4 + quad) ^ c7) * 8);  // kk=1
  const int idxB0 = (wn + col) * 64 + ((quad ^ c7) * 8);
  const int idxB1 = (wn + col) * 64 + (((4 + quad) ^ c7) * 8);

  f4v acc[2][4][4];                   // [A-half][row-frag][col-frag]
  const f4v zz = {0.f, 0.f, 0.f, 0.f};
#pragma unroll
  for (int h = 0; h < 2; ++h)
#pragma unroll
    for (int i = 0; i < 4; ++i)
#pragma unroll
      for (int j = 0; j < 4; ++j) acc[h][i][j] = zz;

  // prologue: tile0 complete + first 3 half-tiles of tile1
  STAGE(0, 0); STAGE(0, 1); STAGE(0, 2); STAGE(0, 3);
  asm volatile("s_waitcnt vmcnt(4)" ::: "memory");
  STAGE(1, 0); STAGE(1, 1); STAGE(1, 2);
  asm volatile("s_waitcnt vmcnt(6)" ::: "memory");   // tile0 fully landed
  __builtin_amdgcn_s_barrier();

  for (int t = 0; t < NT; ++t) {
    const int buf = t & 1;
    const unsigned short* pA = As[buf];
    const unsigned short* pB = Bs[buf];
    s8v a0[4][2], a1[4][2], b0[2][2], b1[2][2];

    // ---------------- P0: read A0+B0, stage (t+1,B1), MFMA A0*B0
#pragma unroll
    for (int x = 0; x < 4; ++x) {
      a0[x][0] = *(const s8v*)&pA[idxA0 + x * 1024];
      a0[x][1] = *(const s8v*)&pA[idxA1 + x * 1024];
    }
#pragma unroll
    for (int u = 0; u < 2; ++u) {
      b0[u][0] = *(const s8v*)&pB[idxB0 + u * 1024];
      b0[u][1] = *(const s8v*)&pB[idxB1 + u * 1024];
    }
    STAGE(t + 1, 3);
    __builtin_amdgcn_s_barrier();
    asm volatile("s_waitcnt lgkmcnt(0)" ::: "memory");
    __builtin_amdgcn_sched_barrier(0);
    __builtin_amdgcn_s_setprio(1);
#pragma unroll
    for (int x = 0; x < 4; ++x)
#pragma unroll
      for (int u = 0; u < 2; ++u) {
        acc[0][x][u] = MFMA16(a0[x][0], b0[u][0], acc[0][x][u]);
        acc[0][x][u] = MFMA16(a0[x][1], b0[u][1], acc[0][x][u]);
      }
    __builtin_amdgcn_s_setprio(0);
    __builtin_amdgcn_sched_barrier(0);
    __builtin_amdgcn_s_barrier();

    // ---------------- P1: read A1, stage (t+2,A0), MFMA A1*B0
#pragma unroll
    for (int x = 0; x < 4; ++x) {
      a1[x][0] = *(const s8v*)&pA[idxA0 + 4096 + x * 1024];
      a1[x][1] = *(const s8v*)&pA[idxA1 + 4096 + x * 1024];
    }
    STAGE(t + 2, 0);
    __builtin_amdgcn_s_barrier();
    asm volatile("s_waitcnt lgkmcnt(0)" ::: "memory");
    __builtin_amdgcn_sched_barrier(0);
    __builtin_amdgcn_s_setprio(1);
#pragma unroll
    for (int x = 0; x < 4; ++x)
#pragma unroll
      for (int u = 0; u < 2; ++u) {
        acc[1][x][u] = MFMA16(a1[x][0], b0[u][0], acc[1][x][u]);
        acc[1][x][u] = MFMA16(a1[x][1], b0[u][1], acc[1][x][u]);
      }
    __builtin_amdgcn_s_setprio(0);
    __builtin_amdgcn_sched_barrier(0);
    __builtin_amdgcn_s_barrier();

    // ---------------- P2: read B1, stage (t+2,B0), MFMA A1*B1
#pragma unroll
    for (int u = 0; u < 2; ++u) {
      b1[u][0] = *(const s8v*)&pB[idxB0 + 2048 + u * 1024];
      b1[u][1] = *(const s8v*)&pB[idxB1 + 2048 + u * 1024];
    }
    STAGE(t + 2, 1);
    __builtin_amdgcn_s_barrier();
    asm volatile("s_waitcnt lgkmcnt(0)" ::: "memory");
    __builtin_amdgcn_sched_barrier(0);
    __builtin_amdgcn_s_setprio(1);
#pragma unroll
    for (int x = 0; x < 4; ++x)
#pragma unroll
      for (int u = 0; u < 2; ++u) {
        acc[1][x][2 + u] = MFMA16(a1[x][0], b1[u][0], acc[1][x][2 + u]);
        acc[1][x][2 + u] = MFMA16(a1[x][1], b1[u][1], acc[1][x][2 + u]);
      }
    __builtin_amdgcn_s_setprio(0);
    __builtin_amdgcn_sched_barrier(0);
    __builtin_amdgcn_s_barrier();

    // ---------------- P3: stage (t+2,A1), MFMA A0*B1, counted vmcnt
    STAGE(t + 2, 2);
    __builtin_amdgcn_s_barrier();
    asm volatile("s_waitcnt lgkmcnt(0)" ::: "memory");
    __builtin_amdgcn_sched_barrier(0);
    __builtin_amdgcn_s_setprio(1);
#pragma unroll
    for (int x = 0; x < 4; ++x)
#pragma unroll
      for (int u = 0; u < 2; ++u) {
        acc[0][x][2 + u] = MFMA16(a0[x][0], b1[u][0], acc[0][x][2 + u]);
        acc[0][x][2 + u] = MFMA16(a0[x][1], b1[u][1], acc[0][x][2 + u]);
      }
    __builtin_amdgcn_s_setprio(0);
    __builtin_amdgcn_sched_barrier(0);
    if (t < NT - 2) asm volatile("s_waitcnt vmcnt(6)" ::: "memory");
    else            asm volatile("s_waitcnt vmcnt(0)" ::: "memory");
    __builtin_amdgcn_s_barrier();
  }

  // epilogue
#pragma unroll
  for (int h = 0; h < 2; ++h) {
#pragma unroll
    for (int i = 0; i < 4; ++i) {
#pragma unroll
      for (int j = 0; j < 4; ++j) {
        int n = n0 + wn + j * 16 + col;
        float bv = bias[n];
#pragma unroll
        for (int r = 0; r < 4; ++r) {
          int m = m0 + wm + h * 64 + i * 16 + quad * 4 + r;
          float v = acc[h][i][j][r] + bv;
          if (OUT_BF16)
            ((unsigned short*)outp)[(size_t)m * N + n] = f2bf(v);
          else
            ((float*)outp)[(size_t)m * N + n] = v;
        }
      }
    }
  }
}

// ---------------------------------------------------------------------------
// kv kernel: grid (64 bh, NCHUNK chunks of 512 rows), 8 subtiles of 64 rows.
//   pkv[chunk][bh][f][d<80] = sum_s k'[s,f]*vext[s,d], vext col 64 = 1.
// R2 structure + T2 XOR-swizzled LDS: stride 64, 16B-chunk ^= (row&7).
// Kills the 8-way bank conflicts on all fragment reads / kps writes.
// ---------------------------------------------------------------------------
__global__ __launch_bounds__(256) void kv_kernel(
    const unsigned short* __restrict__ kg, const unsigned short* __restrict__ vg,
    const unsigned short* __restrict__ rffWT, const float* __restrict__ rffb,
    float* __restrict__ pkv)
{
  __shared__ __align__(16) unsigned short vT[80 * 64];    // swz v^T [d][s], row64=1
  __shared__ __align__(16) unsigned short kps[256 * 64];  // swz k'^T [f][s]
  const int bh = blockIdx.x, chunk = blockIdx.y;
  const int b = bh >> 4, h = bh & 15;
  const int tid = threadIdx.x;
  const int lane = tid & 63, wave = tid >> 6;
  const int col = lane & 15, quad = lane >> 4;
  const int c7 = col & 7;
  const f4v zz = {0.f, 0.f, 0.f, 0.f};

  s8v wf[2][4];
  float bfv[4];
#pragma unroll
  for (int ks = 0; ks < 2; ++ks)
#pragma unroll
    for (int t = 0; t < 4; ++t)
      wf[ks][t] = *(const s8v*)(rffWT +
          (size_t)(wave * 64 + t * 16 + col) * 64 + ks * 32 + quad * 8);
#pragma unroll
  for (int j = 0; j < 4; ++j) bfv[j] = rffb[wave * 64 + j * 16 + col];

  // constant vT rows 64..79 (ones row + zeros), swizzled addressing
  for (int e = tid; e < 1024; e += 256) {
    int r = 64 + (e >> 6), s = e & 63;
    vT[r * 64 + (((s >> 3) ^ (r & 7)) * 8) + (s & 7)] =
        (r == 64) ? (unsigned short)0x3F80 : (unsigned short)0;
  }

  f4v kvacc[4][5];
#pragma unroll
  for (int i = 0; i < 4; ++i)
#pragma unroll
    for (int j = 0; j < 5; ++j) kvacc[i][j] = zz;

  const int sA = tid & 63,         chA = tid >> 6;   // d = chA*8+j, d&7 == j
  const int sB = (tid + 256) & 63, chB = (tid + 256) >> 6;

  union U { s8v v; unsigned short u[8]; };
  U v0, v1;
  s8v kf[2][4];
  {
    const int s0 = chunk * 512;
    v0.v = *(const s8v*)(vg + ((size_t)(b * S_LEN + s0 + sA)) * DMODEL + h * KDIM + chA * 8);
    v1.v = *(const s8v*)(vg + ((size_t)(b * S_LEN + s0 + sB)) * DMODEL + h * KDIM + chB * 8);
#pragma unroll
    for (int ks = 0; ks < 2; ++ks)
#pragma unroll
      for (int t = 0; t < 4; ++t)
        kf[ks][t] = *(const s8v*)(kg +
            ((size_t)(b * S_LEN + s0 + t * 16 + col)) * DMODEL + h * KDIM + ks * 32 + quad * 8);
  }

  for (int st = 0; st < 8; ++st) {
    const int s0 = chunk * 512 + st * 64;
    __syncthreads();   // previous kv-MFMA done reading vT/kps
    // write v^T rows 0..63 from preloaded regs (swizzled)
#pragma unroll
    for (int j = 0; j < 8; ++j)
      vT[(chA * 8 + j) * 64 + (((sA >> 3) ^ j) * 8) + (sA & 7)] = v0.u[j];
#pragma unroll
    for (int j = 0; j < 8; ++j)
      vT[(chB * 8 + j) * 64 + (((sB >> 3) ^ j) * 8) + (sB & 7)] = v1.u[j];
    // proj MFMA: A = preloaded k-frags, B = registers
    f4v p[4][4];
#pragma unroll
    for (int i = 0; i < 4; ++i)
#pragma unroll
      for (int j = 0; j < 4; ++j) p[i][j] = zz;
#pragma unroll
    for (int ks = 0; ks < 2; ++ks)
#pragma unroll
      for (int i = 0; i < 4; ++i)
#pragma unroll
        for (int j = 0; j < 4; ++j) p[i][j] = MFMA16(kf[ks][i], wf[ks][j], p[i][j]);
    // prefetch next subtile (drains under cos + kv-MFMA)
    U n0, n1;
    s8v kn[2][4];
    if (st < 7) {
      const int s1 = s0 + 64;
      n0.v = *(const s8v*)(vg + ((size_t)(b * S_LEN + s1 + sA)) * DMODEL + h * KDIM + chA * 8);
      n1.v = *(const s8v*)(vg + ((size_t)(b * S_LEN + s1 + sB)) * DMODEL + h * KDIM + chB * 8);
#pragma unroll
      for (int ks = 0; ks < 2; ++ks)
#pragma unroll
        for (int t = 0; t < 4; ++t)
          kn[ks][t] = *(const s8v*)(kg +
              ((size_t)(b * S_LEN + s1 + t * 16 + col)) * DMODEL + h * KDIM + ks * 32 + quad * 8);
    }
    // cos epilogue -> kps (swizzled), packed 4x bf16 per ds_write_b64
#pragma unroll
    for (int j = 0; j < 4; ++j) {
      int f = wave * 64 + j * 16 + col;    // f&7 == c7
#pragma unroll
      for (int i = 0; i < 4; ++i) {
        union { unsigned long long d; unsigned short u[4]; } pk;
#pragma unroll
        for (int r = 0; r < 4; ++r)
          pk.u[r] = f2bf(__cosf(p[i][j][r] + bfv[j]) * RFF_SCALE);
        int sc = i * 2 + (quad >> 1);      // (i*16+quad*4)>>3
        *(unsigned long long*)&kps[f * 64 + ((sc ^ c7) * 8) + (quad & 1) * 4] = pk.d;
      }
    }
    __syncthreads();   // kps + vT visible
    // kv MFMA: A = kps (wave's f-range), B = vT — swizzled reads
#pragma unroll
    for (int ks = 0; ks < 2; ++ks) {
      s8v af[4], bf[5];
#pragma unroll
      for (int t = 0; t < 4; ++t)
        af[t] = *(const s8v*)&kps[(wave * 64 + t * 16 + col) * 64 +
                                  (((ks * 4 + quad) ^ c7) * 8)];
#pragma unroll
      for (int t = 0; t < 5; ++t)
        bf[t] = *(const s8v*)&vT[(t * 16 + col) * 64 +
                                 (((ks * 4 + quad) ^ c7) * 8)];
#pragma unroll
      for (int i = 0; i < 4; ++i)
#pragma unroll
        for (int j = 0; j < 5; ++j)
          kvacc[i][j] = MFMA16(af[i], bf[j], kvacc[i][j]);
    }
    if (st < 7) {
      v0 = n0; v1 = n1;
#pragma unroll
      for (int ks = 0; ks < 2; ++ks)
#pragma unroll
        for (int t = 0; t < 4; ++t) kf[ks][t] = kn[ks][t];
    }
  }
  const size_t base = ((size_t)(chunk * 64 + bh)) * NF * 80;
#pragma unroll
  for (int i = 0; i < 4; ++i)
#pragma unroll
    for (int r = 0; r < 4; ++r) {
      int f = wave * 64 + i * 16 + quad * 4 + r;
#pragma unroll
      for (int j = 0; j < 5; ++j)
        pkv[base + (size_t)f * 80 + j * 16 + col] = kvacc[i][j][r];
    }
}

// ---------------------------------------------------------------------------
// reduce NCHUNK chunk partials, transpose -> kvT bf16 [bh][80 d][256 f]
// lt padded to stride 66 (d-stride 64 elem = 32 dwords was a 32-way conflict).
// ---------------------------------------------------------------------------
__global__ __launch_bounds__(256) void reduce_kv_kernel(
    const float* __restrict__ pkv, unsigned short* __restrict__ kvT)
{
  __shared__ unsigned short lt[80 * 66];
  const int bh = blockIdx.x >> 2, qt = blockIdx.x & 3;
  const int f0 = qt * 64;
  for (int e = threadIdx.x; e < 64 * 80; e += 256) {
    int fl = e / 80, d = e - fl * 80;
    float s = 0.f;
#pragma unroll
    for (int c = 0; c < NCHUNK; ++c)
      s += pkv[((size_t)(c * 64 + bh)) * NF * 80 + (size_t)(f0 + fl) * 80 + d];
    lt[d * 66 + fl] = f2bf(s);
  }
  __syncthreads();
  for (int o = threadIdx.x; o < 80 * 64; o += 256) {
    int d = o >> 6, fl = o & 63;
    kvT[(size_t)bh * 80 * NF + d * 256 + f0 + fl] = lt[d * 66 + fl];
  }
}

// ---------------------------------------------------------------------------
// attn kernel: grid (64 bh, 8), 8 x 64-row tiles per block.
//   q' = cos(q @ rffWT^T + b)*scale; num = q' @ kvT^T; att = num/(den+eps)
// R2 structure + T2 XOR-swizzled LDS (stride 256, chunk ^= row&7).
// ---------------------------------------------------------------------------
__global__ __launch_bounds__(256) void attn_kernel(
    const unsigned short* __restrict__ qg, const unsigned short* __restrict__ kvTg,
    const unsigned short* __restrict__ rffWT, const float* __restrict__ rffb,
    unsigned short* __restrict__ att)
{
  __shared__ __align__(16) unsigned short qps[64 * 256];   // swz q' [s][f]
  __shared__ __align__(16) unsigned short kvs[80 * 256];   // swz kvT [d][f]
  const int bh = blockIdx.x;
  const int b = bh >> 4, h = bh & 15;
  const int tid = threadIdx.x;
  const int lane = tid & 63, wave = tid >> 6;
  const int col = lane & 15, quad = lane >> 4;
  const int c7 = col & 7;
  const f4v zz = {0.f, 0.f, 0.f, 0.f};

  s8v wf[2][4];
  float bfv[4];
#pragma unroll
  for (int ks = 0; ks < 2; ++ks)
#pragma unroll
    for (int t = 0; t < 4; ++t)
      wf[ks][t] = *(const s8v*)(rffWT +
          (size_t)(wave * 64 + t * 16 + col) * 64 + ks * 32 + quad * 8);
#pragma unroll
  for (int j = 0; j < 4; ++j) bfv[j] = rffb[wave * 64 + j * 16 + col];

  // stage kv [80][256] -> kvs, swizzled chunks
  for (int c = tid; c < 2560; c += 256) {
    int d = c >> 5, ch = c & 31;
    *(s8v*)&kvs[d * 256 + ((ch ^ (d & 7)) * 8)] =
        *(const s8v*)(kvTg + (size_t)bh * 80 * NF + d * 256 + ch * 8);
  }

  s8v qf[2][4];
  {
    const int s0 = blockIdx.y * 512;
#pragma unroll
    for (int ks = 0; ks < 2; ++ks)
#pragma unroll
      for (int t = 0; t < 4; ++t)
        qf[ks][t] = *(const s8v*)(qg +
            ((size_t)(b * S_LEN + s0 + t * 16 + col)) * DMODEL + h * KDIM + ks * 32 + quad * 8);
  }

  for (int it = 0; it < 8; ++it) {
    const int s0 = blockIdx.y * 512 + it * 64;
    // proj: A = preloaded q-frags, B = registers
    f4v p[4][4];
#pragma unroll
    for (int i = 0; i < 4; ++i)
#pragma unroll
      for (int j = 0; j < 4; ++j) p[i][j] = zz;
#pragma unroll
    for (int ks = 0; ks < 2; ++ks)
#pragma unroll
      for (int i = 0; i < 4; ++i)
#pragma unroll
        for (int j = 0; j < 4; ++j) p[i][j] = MFMA16(qf[ks][i], wf[ks][j], p[i][j]);
    // prefetch next tile's q-frags (drains under cos + num-MFMA)
    s8v qn[2][4];
    if (it < 7) {
      const int s1 = s0 + 64;
#pragma unroll
      for (int ks = 0; ks < 2; ++ks)
#pragma unroll
        for (int t = 0; t < 4; ++t)
          qn[ks][t] = *(const s8v*)(qg +
              ((size_t)(b * S_LEN + s1 + t * 16 + col)) * DMODEL + h * KDIM + ks * 32 + quad * 8);
    }
    __syncthreads();   // previous num-MFMA done reading qps (also fences kvs stage)
    // cos writes -> qps (swizzled): elem (s,f) at s*256 + ((f>>3 ^ s&7)*8) + f&7
#pragma unroll
    for (int j = 0; j < 4; ++j) {
      int fc = wave * 8 + j * 2 + (col >> 3);   // f>>3
#pragma unroll
      for (int i = 0; i < 4; ++i)
#pragma unroll
        for (int r = 0; r < 4; ++r) {
          int s = i * 16 + quad * 4 + r;
          int s7 = (quad & 1) * 4 + r;          // s&7
          qps[s * 256 + ((fc ^ s7) * 8) + c7] =
              f2bf(__cosf(p[i][j][r] + bfv[j]) * RFF_SCALE);
        }
    }
    __syncthreads();
    // num: A = qps rows wave*16..+15, B = kvs, K=256 — swizzled reads
    f4v acc[5];
#pragma unroll
    for (int j = 0; j < 5; ++j) acc[j] = zz;
#pragma unroll
    for (int k0 = 0; k0 < 256; k0 += 32) {
      const int kc = k0 >> 3;
      s8v af = *(const s8v*)&qps[(wave * 16 + col) * 256 + (((kc + quad) ^ c7) * 8)];
      s8v bf[5];
#pragma unroll
      for (int t = 0; t < 5; ++t)
        bf[t] = *(const s8v*)&kvs[(t * 16 + col) * 256 + (((kc + quad) ^ c7) * 8)];
#pragma unroll
      for (int j = 0; j < 5; ++j) acc[j] = MFMA16(af, bf[j], acc[j]);
    }
    float inv[4];
#pragma unroll
    for (int r = 0; r < 4; ++r) {
      float den = __shfl(acc[4][r], lane & 48);
      inv[r] = 1.0f / (den + 1e-6f);
    }
#pragma unroll
    for (int r = 0; r < 4; ++r) {
      int m = s0 + wave * 16 + quad * 4 + r;
      size_t obase = ((size_t)(b * S_LEN + m)) * DMODEL + h * KDIM;
#pragma unroll
      for (int j = 0; j < 4; ++j)
        att[obase + j * 16 + col] = f2bf(acc[j][r] * inv[r]);
    }
    if (it < 7) {
#pragma unroll
      for (int ks = 0; ks < 2; ++ks)
#pragma unroll
        for (int t = 0; t < 4; ++t) qf[ks][t] = qn[ks][t];
    }
  }
}

// ---------------------------------------------------------------------------
// kernel_launch. inputs: 0:x 1:Wq 2:bq 3:Wk 4:bk 5:Wv 6:bv 7:rff_W 8:rff_b 9:Wo 10:bo
// ---------------------------------------------------------------------------
extern "C" void kernel_launch(void* const* d_in, const int* in_sizes, int n_in,
                              void* d_out, int out_size, void* d_ws, size_t ws_size,
                              hipStream_t stream)
{
  const float* x    = (const float*)d_in[0];
  const float* Wq   = (const float*)d_in[1];
  const float* bq   = (const float*)d_in[2];
  const float* Wk   = (const float*)d_in[3];
  const float* bk   = (const float*)d_in[4];
  const float* Wv   = (const float*)d_in[5];
  const float* bv   = (const float*)d_in[6];
  const float* rffW = (const float*)d_in[7];
  const float* rffb = (const float*)d_in[8];
  const float* Wo   = (const float*)d_in[9];
  const float* bo   = (const float*)d_in[10];
  float* out = (float*)d_out;

  char* w = (char*)d_ws;
  const size_t XB = (size_t)NROWS * DMODEL * 2;     // 33,554,432
  const size_t WT = (size_t)DMODEL * DMODEL * 2;    // 2,097,152
  unsigned short* xb   = (unsigned short*)(w);
  unsigned short* WqT  = (unsigned short*)(w + XB);
  unsigned short* WkT  = (unsigned short*)(w + XB + WT);
  unsigned short* WvT  = (unsigned short*)(w + XB + 2 * WT);
  unsigned short* WoT  = (unsigned short*)(w + XB + 3 * WT);
  unsigned short* rWT  = (unsigned short*)(w + XB + 4 * WT);
  char* p = w + XB + 4 * WT + 65536;
  unsigned short* qb = (unsigned short*)(p);
  unsigned short* kb = (unsigned short*)(p + XB);
  unsigned short* vb = (unsigned short*)(p + 2 * XB);
  float* pkv         = (float*)(p + 3 * XB);
  unsigned short* kvT = (unsigned short*)(p + 3 * XB + (size_t)NCHUNK * 64 * NF * 80 * 4);
  unsigned short* att = kb;   // kb consumed before attn writes

  cast_bf16_kernel<<<NROWS * DMODEL / 8 / 256, 256, 0, stream>>>(x, xb, NROWS * DMODEL / 8);
  dim3 tg(32, 32);
  transpose_cast_kernel<<<tg, 256, 0, stream>>>(Wq, WqT);
  transpose_cast_kernel<<<tg, 256, 0, stream>>>(Wk, WkT);
  transpose_cast_kernel<<<tg, 256, 0, stream>>>(Wv, WvT);
  transpose_cast_kernel<<<tg, 256, 0, stream>>>(Wo, WoT);
  prep_rff_kernel<<<64, 256, 0, stream>>>(rffW, rWT);

  // fused QKV: 64 m-tiles x 12 n-tiles (4 per weight matrix)
  gemm_bt_kernel<1, 1><<<768, 512, 0, stream>>>(
      xb, WqT, WkT, WvT, bq, bk, bv, qb, kb, vb, NROWS, DMODEL, DMODEL, 12);

  kv_kernel<<<dim3(64, NCHUNK), 256, 0, stream>>>(kb, vb, rWT, rffb, pkv);
  reduce_kv_kernel<<<256, 256, 0, stream>>>(pkv, kvT);
  attn_kernel<<<dim3(64, 8), 256, 0, stream>>>(qb, kvT, rWT, rffb, att);

  // out-proj: 64 m-tiles x 4 n-tiles
  gemm_bt_kernel<0, 0><<<256, 512, 0, stream>>>(
      att, WoT, nullptr, nullptr, bo, nullptr, nullptr, out, nullptr, nullptr,
      NROWS, DMODEL, DMODEL, 4);
}

// Round 7
// 389.172 us; speedup vs baseline: 1.0669x; 1.0669x over previous
//
#include <hip/hip_runtime.h>
#include <hip/hip_bf16.h>
#include <math.h>

#define B_SZ    4
#define S_LEN   4096
#define DMODEL  1024
#define NH      16
#define KDIM    64
#define NF      256
#define NROWS   (B_SZ * S_LEN)          // 16384
#define NCHUNK  8                       // kv partial chunks (512 rows each)
#define RFF_SCALE 0.08838834764831845f  // sqrt(2/256)
#define NORM_Q    0.125f                // 1/sqrt(64)

typedef __attribute__((ext_vector_type(8))) short s8v;
typedef __attribute__((ext_vector_type(4))) float f4v;

static __device__ __forceinline__ unsigned short f2bf(float f) {
  unsigned u = __float_as_uint(f);
  unsigned r = (u + 0x7FFFu + ((u >> 16) & 1u)) >> 16;   // RNE
  return (unsigned short)r;
}

#define MFMA16(a, b, c) __builtin_amdgcn_mfma_f32_16x16x32_bf16((a), (b), (c), 0, 0, 0)

// async global->LDS, 16B per lane. LDS dest is wave-uniform base + lane*16.
__device__ __forceinline__ void glds16(const void* g, void* l) {
  __builtin_amdgcn_global_load_lds(
      (const __attribute__((address_space(1))) void*)g,
      (__attribute__((address_space(3))) void*)l, 16, 0, 0);
}

// ---------------------------------------------------------------------------
// unified prep kernel: one launch replaces cast + 4 transposes + prep_rff.
// blocks [0,8192): cast x fp32->bf16 (8 elems/thread)
// blocks [8192,12288): transpose+cast one of Wq/Wk/Wv/Wo (1024 blocks each)
// blocks [12288,12352): rffW -> rffWT with NORM folded
// Branch is block-uniform, so the transpose barrier is safe.
// ---------------------------------------------------------------------------
__global__ __launch_bounds__(256) void prep_kernel(
    const float* __restrict__ x, unsigned short* __restrict__ xb,
    const float* __restrict__ Wq, unsigned short* __restrict__ WqT,
    const float* __restrict__ Wk, unsigned short* __restrict__ WkT,
    const float* __restrict__ Wv, unsigned short* __restrict__ WvT,
    const float* __restrict__ Wo, unsigned short* __restrict__ WoT,
    const float* __restrict__ rffW, unsigned short* __restrict__ rffWT)
{
  __shared__ float t[32][33];
  int blk = blockIdx.x;
  if (blk < 8192) {
    // ---- cast path
    int i = blk * 256 + threadIdx.x;            // < 2097152 exactly
    const float* s = x + (size_t)i * 8;
    float4 a = *(const float4*)s;
    float4 b = *(const float4*)(s + 4);
    union { s8v v; unsigned short u[8]; } o;
    o.u[0]=f2bf(a.x); o.u[1]=f2bf(a.y); o.u[2]=f2bf(a.z); o.u[3]=f2bf(a.w);
    o.u[4]=f2bf(b.x); o.u[5]=f2bf(b.y); o.u[6]=f2bf(b.z); o.u[7]=f2bf(b.w);
    *(s8v*)(xb + (size_t)i * 8) = o.v;
    return;
  }
  blk -= 8192;
  if (blk < 4096) {
    // ---- transpose path
    const int wsel = blk >> 10, b2 = blk & 1023;
    const float* W = (wsel == 0) ? Wq : (wsel == 1) ? Wk : (wsel == 2) ? Wv : Wo;
    unsigned short* WT = (wsel == 0) ? WqT : (wsel == 1) ? WkT : (wsel == 2) ? WvT : WoT;
    const int n0 = (b2 & 31) * 32, k0 = (b2 >> 5) * 32;
    const int c = threadIdx.x & 31, r4 = threadIdx.x >> 5;
#pragma unroll
    for (int i = 0; i < 4; ++i) {
      int row = r4 + i * 8;
      t[row][c] = W[(size_t)(k0 + row) * 1024 + n0 + c];
    }
    __syncthreads();
#pragma unroll
    for (int i = 0; i < 4; ++i) {
      int row = r4 + i * 8;
      WT[(size_t)(n0 + row) * 1024 + k0 + c] = f2bf(t[c][row]);
    }
    return;
  }
  blk -= 4096;
  // ---- rff path
  int i = blk * 256 + threadIdx.x;              // 16384
  int f = i >> 6, d = i & 63;
  rffWT[(size_t)f * 64 + d] = f2bf(rffW[(size_t)d * 256 + f] * NORM_Q);
}

// ---------------------------------------------------------------------------
// bf16 MFMA GEMM, 256x256 tile / BK=64 / 8 waves / 8-phase schedule.
// ROUND-1 VERSION VERBATIM (best measured: 115 us QKV, 0 bank conflicts).
// ---------------------------------------------------------------------------
template <int OUT_BF16, int QKV_FUSED>
__global__ __launch_bounds__(512, 2) void gemm_bt_kernel(
    const unsigned short* __restrict__ A,
    const unsigned short* __restrict__ BT0,
    const unsigned short* __restrict__ BT1,
    const unsigned short* __restrict__ BT2,
    const float* __restrict__ bias0, const float* __restrict__ bias1,
    const float* __restrict__ bias2,
    void* __restrict__ out0, void* __restrict__ out1, void* __restrict__ out2,
    int M, int N, int K, int NXT)
{
  __shared__ __align__(16) unsigned short As[2][16384];   // 64 KiB
  __shared__ __align__(16) unsigned short Bs[2][16384];   // 64 KiB
  const int tid = threadIdx.x;
  const int lane = tid & 63, wave = tid >> 6;

  // bijective XCD-aware swizzle on flattened workgroup id (m204)
  int wg = blockIdx.x;
  {
    const int nwg = gridDim.x;
    const int q = nwg >> 3, r = nwg & 7;
    const int xcd = wg & 7, pos = wg >> 3;
    wg = (xcd < r ? xcd * (q + 1) : r * (q + 1) + (xcd - r) * q) + pos;
  }
  const int m0 = (wg / NXT) * 256;
  int ngl = (wg % NXT) * 256;
  const unsigned short* BT = BT0;
  const float* bias = bias0;
  void* outp = out0;
  if (QKV_FUSED) {
    int which = ngl >> 10;
    if (which == 1) { BT = BT1; bias = bias1; outp = out1; }
    else if (which == 2) { BT = BT2; bias = bias2; outp = out2; }
    ngl &= 1023;
  }
  const int n0 = ngl;

  // staging addressing: thread covers LDS row trow, 16B chunk (lane&7).
  const int trow = tid >> 3;                       // 0..63
  const int g8 = (((lane & 7) ^ (trow & 7)) * 8);  // swizzled col (elements)
  const unsigned short* aPtr = A  + (size_t)(m0 + trow) * K + g8;
  const unsigned short* bPtr = BT + (size_t)(n0 + trow) * K + g8;
  const int NT = K >> 6;

  auto STAGE = [&](int ts, int h) {   // h: 0=A0 1=B0 2=A1 3=B1
    if (ts >= NT) return;
    const int buf = ts & 1, half = h >> 1;
    const size_t go = (size_t)half * 128 * K + (size_t)ts * 64;
    if ((h & 1) == 0) {
      unsigned short* lp = &As[buf][half * 8192 + wave * 512];
      glds16(aPtr + go, lp);
      glds16(aPtr + go + (size_t)64 * K, lp + 4096);
    } else {
      unsigned short* lp = &Bs[buf][half * 8192 + wave * 512];
      glds16(bPtr + go, lp);
      glds16(bPtr + go + (size_t)64 * K, lp + 4096);
    }
  };

  // fragment read addressing (swizzled: chunk ^= row&7; row&7 == col&7)
  const int col = lane & 15, quad = lane >> 4;
  const int wm = (wave >> 2) * 128;   // wave row base (2 row-waves)
  const int wn = (wave & 3) * 64;     // wave col base (4 col-waves)
  const int c7 = col & 7;
  const int idxA0 = (wm + col) * 64 + ((quad ^ c7) * 8);        // kk=0
  const int idxA1 = (wm + col) * 64 + (((4 + quad) ^ c7) * 8);  // kk=1
  const int idxB0 = (wn + col) * 64 + ((quad ^ c7) * 8);
  const int idxB1 = (wn + col) * 64 + (((4 + quad) ^ c7) * 8);

  f4v acc[2][4][4];                   // [A-half][row-frag][col-frag]
  const f4v zz = {0.f, 0.f, 0.f, 0.f};
#pragma unroll
  for (int h = 0; h < 2; ++h)
#pragma unroll
    for (int i = 0; i < 4; ++i)
#pragma unroll
      for (int j = 0; j < 4; ++j) acc[h][i][j] = zz;

  // prologue: tile0 complete + first 3 half-tiles of tile1
  STAGE(0, 0); STAGE(0, 1); STAGE(0, 2); STAGE(0, 3);
  asm volatile("s_waitcnt vmcnt(4)" ::: "memory");
  STAGE(1, 0); STAGE(1, 1); STAGE(1, 2);
  asm volatile("s_waitcnt vmcnt(6)" ::: "memory");   // tile0 fully landed
  __builtin_amdgcn_s_barrier();

  for (int t = 0; t < NT; ++t) {
    const int buf = t & 1;
    const unsigned short* pA = As[buf];
    const unsigned short* pB = Bs[buf];
    s8v a0[4][2], a1[4][2], b0[2][2], b1[2][2];

    // ---------------- P0: read A0+B0, stage (t+1,B1), MFMA A0*B0
#pragma unroll
    for (int x = 0; x < 4; ++x) {
      a0[x][0] = *(const s8v*)&pA[idxA0 + x * 1024];
      a0[x][1] = *(const s8v*)&pA[idxA1 + x * 1024];
    }
#pragma unroll
    for (int u = 0; u < 2; ++u) {
      b0[u][0] = *(const s8v*)&pB[idxB0 + u * 1024];
      b0[u][1] = *(const s8v*)&pB[idxB1 + u * 1024];
    }
    STAGE(t + 1, 3);
    __builtin_amdgcn_s_barrier();
    asm volatile("s_waitcnt lgkmcnt(0)" ::: "memory");
    __builtin_amdgcn_sched_barrier(0);
    __builtin_amdgcn_s_setprio(1);
#pragma unroll
    for (int x = 0; x < 4; ++x)
#pragma unroll
      for (int u = 0; u < 2; ++u) {
        acc[0][x][u] = MFMA16(a0[x][0], b0[u][0], acc[0][x][u]);
        acc[0][x][u] = MFMA16(a0[x][1], b0[u][1], acc[0][x][u]);
      }
    __builtin_amdgcn_s_setprio(0);
    __builtin_amdgcn_sched_barrier(0);
    __builtin_amdgcn_s_barrier();

    // ---------------- P1: read A1, stage (t+2,A0), MFMA A1*B0
#pragma unroll
    for (int x = 0; x < 4; ++x) {
      a1[x][0] = *(const s8v*)&pA[idxA0 + 4096 + x * 1024];
      a1[x][1] = *(const s8v*)&pA[idxA1 + 4096 + x * 1024];
    }
    STAGE(t + 2, 0);
    __builtin_amdgcn_s_barrier();
    asm volatile("s_waitcnt lgkmcnt(0)" ::: "memory");
    __builtin_amdgcn_sched_barrier(0);
    __builtin_amdgcn_s_setprio(1);
#pragma unroll
    for (int x = 0; x < 4; ++x)
#pragma unroll
      for (int u = 0; u < 2; ++u) {
        acc[1][x][u] = MFMA16(a1[x][0], b0[u][0], acc[1][x][u]);
        acc[1][x][u] = MFMA16(a1[x][1], b0[u][1], acc[1][x][u]);
      }
    __builtin_amdgcn_s_setprio(0);
    __builtin_amdgcn_sched_barrier(0);
    __builtin_amdgcn_s_barrier();

    // ---------------- P2: read B1, stage (t+2,B0), MFMA A1*B1
#pragma unroll
    for (int u = 0; u < 2; ++u) {
      b1[u][0] = *(const s8v*)&pB[idxB0 + 2048 + u * 1024];
      b1[u][1] = *(const s8v*)&pB[idxB1 + 2048 + u * 1024];
    }
    STAGE(t + 2, 1);
    __builtin_amdgcn_s_barrier();
    asm volatile("s_waitcnt lgkmcnt(0)" ::: "memory");
    __builtin_amdgcn_sched_barrier(0);
    __builtin_amdgcn_s_setprio(1);
#pragma unroll
    for (int x = 0; x < 4; ++x)
#pragma unroll
      for (int u = 0; u < 2; ++u) {
        acc[1][x][2 + u] = MFMA16(a1[x][0], b1[u][0], acc[1][x][2 + u]);
        acc[1][x][2 + u] = MFMA16(a1[x][1], b1[u][1], acc[1][x][2 + u]);
      }
    __builtin_amdgcn_s_setprio(0);
    __builtin_amdgcn_sched_barrier(0);
    __builtin_amdgcn_s_barrier();

    // ---------------- P3: stage (t+2,A1), MFMA A0*B1, counted vmcnt
    STAGE(t + 2, 2);
    __builtin_amdgcn_s_barrier();
    asm volatile("s_waitcnt lgkmcnt(0)" ::: "memory");
    __builtin_amdgcn_sched_barrier(0);
    __builtin_amdgcn_s_setprio(1);
#pragma unroll
    for (int x = 0; x < 4; ++x)
#pragma unroll
      for (int u = 0; u < 2; ++u) {
        acc[0][x][2 + u] = MFMA16(a0[x][0], b1[u][0], acc[0][x][2 + u]);
        acc[0][x][2 + u] = MFMA16(a0[x][1], b1[u][1], acc[0][x][2 + u]);
      }
    __builtin_amdgcn_s_setprio(0);
    __builtin_amdgcn_sched_barrier(0);
    if (t < NT - 2) asm volatile("s_waitcnt vmcnt(6)" ::: "memory");
    else            asm volatile("s_waitcnt vmcnt(0)" ::: "memory");
    __builtin_amdgcn_s_barrier();
  }

  // epilogue
#pragma unroll
  for (int h = 0; h < 2; ++h) {
#pragma unroll
    for (int i = 0; i < 4; ++i) {
#pragma unroll
      for (int j = 0; j < 4; ++j) {
        int n = n0 + wn + j * 16 + col;
        float bv = bias[n];
#pragma unroll
        for (int r = 0; r < 4; ++r) {
          int m = m0 + wm + h * 64 + i * 16 + quad * 4 + r;
          float v = acc[h][i][j][r] + bv;
          if (OUT_BF16)
            ((unsigned short*)outp)[(size_t)m * N + n] = f2bf(v);
          else
            ((float*)outp)[(size_t)m * N + n] = v;
        }
      }
    }
  }
}

// ---------------------------------------------------------------------------
// kv kernel: grid (64 bh, NCHUNK chunks of 512 rows), 8 subtiles of 64 rows.
//   pkv[chunk][bh][f][d<80] = sum_s k'[s,f]*vext[s,d], vext col 64 = 1.
// R2-EXACT VERSION (best measured midchain): prefetch after proj-MFMA,
// packed ds_write_b64 kps, 5-tile kvacc.
// ---------------------------------------------------------------------------
__global__ __launch_bounds__(256) void kv_kernel(
    const unsigned short* __restrict__ kg, const unsigned short* __restrict__ vg,
    const unsigned short* __restrict__ rffWT, const float* __restrict__ rffb,
    float* __restrict__ pkv)
{
  __shared__ __align__(16) unsigned short vT[80 * 72];    // v^T [d][s], row64=1
  __shared__ __align__(16) unsigned short kps[256 * 72];  // k'^T [f][s]
  const int bh = blockIdx.x, chunk = blockIdx.y;
  const int b = bh >> 4, h = bh & 15;
  const int tid = threadIdx.x;
  const int lane = tid & 63, wave = tid >> 6;
  const int col = lane & 15, quad = lane >> 4;
  const f4v zz = {0.f, 0.f, 0.f, 0.f};

  s8v wf[2][4];
  float bfv[4];
#pragma unroll
  for (int ks = 0; ks < 2; ++ks)
#pragma unroll
    for (int t = 0; t < 4; ++t)
      wf[ks][t] = *(const s8v*)(rffWT +
          (size_t)(wave * 64 + t * 16 + col) * 64 + ks * 32 + quad * 8);
#pragma unroll
  for (int j = 0; j < 4; ++j) bfv[j] = rffb[wave * 64 + j * 16 + col];

  // constant vT rows 64..79 (ones row + zeros)
  for (int e = tid; e < 1024; e += 256) {
    int r = 64 + (e >> 6), s = e & 63;
    vT[r * 72 + s] = (r == 64) ? (unsigned short)0x3F80 : (unsigned short)0;
  }

  f4v kvacc[4][5];
#pragma unroll
  for (int i = 0; i < 4; ++i)
#pragma unroll
    for (int j = 0; j < 5; ++j) kvacc[i][j] = zz;

  const int sA = tid & 63,         chA = tid >> 6;
  const int sB = (tid + 256) & 63, chB = (tid + 256) >> 6;

  union U { s8v v; unsigned short u[8]; };
  U v0, v1;
  s8v kf[2][4];
  {
    const int s0 = chunk * 512;
    v0.v = *(const s8v*)(vg + ((size_t)(b * S_LEN + s0 + sA)) * DMODEL + h * KDIM + chA * 8);
    v1.v = *(const s8v*)(vg + ((size_t)(b * S_LEN + s0 + sB)) * DMODEL + h * KDIM + chB * 8);
#pragma unroll
    for (int ks = 0; ks < 2; ++ks)
#pragma unroll
      for (int t = 0; t < 4; ++t)
        kf[ks][t] = *(const s8v*)(kg +
            ((size_t)(b * S_LEN + s0 + t * 16 + col)) * DMODEL + h * KDIM + ks * 32 + quad * 8);
  }

  for (int st = 0; st < 8; ++st) {
    const int s0 = chunk * 512 + st * 64;
    __syncthreads();   // previous kv-MFMA done reading vT/kps
    // write v^T rows 0..63 from preloaded regs
#pragma unroll
    for (int j = 0; j < 8; ++j) vT[(chA * 8 + j) * 72 + sA] = v0.u[j];
#pragma unroll
    for (int j = 0; j < 8; ++j) vT[(chB * 8 + j) * 72 + sB] = v1.u[j];
    // proj MFMA: A = preloaded k-frags, B = registers
    f4v p[4][4];
#pragma unroll
    for (int i = 0; i < 4; ++i)
#pragma unroll
      for (int j = 0; j < 4; ++j) p[i][j] = zz;
#pragma unroll
    for (int ks = 0; ks < 2; ++ks)
#pragma unroll
      for (int i = 0; i < 4; ++i)
#pragma unroll
        for (int j = 0; j < 4; ++j) p[i][j] = MFMA16(kf[ks][i], wf[ks][j], p[i][j]);
    // prefetch next subtile (drains under cos + kv-MFMA)
    U n0, n1;
    s8v kn[2][4];
    if (st < 7) {
      const int s1 = s0 + 64;
      n0.v = *(const s8v*)(vg + ((size_t)(b * S_LEN + s1 + sA)) * DMODEL + h * KDIM + chA * 8);
      n1.v = *(const s8v*)(vg + ((size_t)(b * S_LEN + s1 + sB)) * DMODEL + h * KDIM + chB * 8);
#pragma unroll
      for (int ks = 0; ks < 2; ++ks)
#pragma unroll
        for (int t = 0; t < 4; ++t)
          kn[ks][t] = *(const s8v*)(kg +
              ((size_t)(b * S_LEN + s1 + t * 16 + col)) * DMODEL + h * KDIM + ks * 32 + quad * 8);
    }
    // cos epilogue -> kps[f][s], packed 4x bf16 per ds_write_b64
#pragma unroll
    for (int j = 0; j < 4; ++j) {
      int f = wave * 64 + j * 16 + col;
#pragma unroll
      for (int i = 0; i < 4; ++i) {
        union { unsigned long long d; unsigned short u[4]; } pk;
#pragma unroll
        for (int r = 0; r < 4; ++r)
          pk.u[r] = f2bf(__cosf(p[i][j][r] + bfv[j]) * RFF_SCALE);
        *(unsigned long long*)&kps[f * 72 + i * 16 + quad * 4] = pk.d;
      }
    }
    __syncthreads();   // kps + vT visible
    // kv MFMA: A = kps (wave's f-range), B = vT
#pragma unroll
    for (int ks = 0; ks < 2; ++ks) {
      s8v af[4], bf[5];
#pragma unroll
      for (int t = 0; t < 4; ++t)
        af[t] = *(const s8v*)&kps[(wave * 64 + t * 16 + col) * 72 + ks * 32 + quad * 8];
#pragma unroll
      for (int t = 0; t < 5; ++t)
        bf[t] = *(const s8v*)&vT[(t * 16 + col) * 72 + ks * 32 + quad * 8];
#pragma unroll
      for (int i = 0; i < 4; ++i)
#pragma unroll
        for (int j = 0; j < 5; ++j)
          kvacc[i][j] = MFMA16(af[i], bf[j], kvacc[i][j]);
    }
    if (st < 7) {
      v0 = n0; v1 = n1;
#pragma unroll
      for (int ks = 0; ks < 2; ++ks)
#pragma unroll
        for (int t = 0; t < 4; ++t) kf[ks][t] = kn[ks][t];
    }
  }
  const size_t base = ((size_t)(chunk * 64 + bh)) * NF * 80;
#pragma unroll
  for (int i = 0; i < 4; ++i)
#pragma unroll
    for (int r = 0; r < 4; ++r) {
      int f = wave * 64 + i * 16 + quad * 4 + r;
#pragma unroll
      for (int j = 0; j < 5; ++j)
        pkv[base + (size_t)f * 80 + j * 16 + col] = kvacc[i][j][r];
    }
}

// ---------------------------------------------------------------------------
// reduce NCHUNK chunk partials, transpose -> kvT bf16 [bh][80 d][256 f]
// lt padded to stride 66 (d-stride 64 elem was a 32-way write conflict).
// ---------------------------------------------------------------------------
__global__ __launch_bounds__(256) void reduce_kv_kernel(
    const float* __restrict__ pkv, unsigned short* __restrict__ kvT)
{
  __shared__ unsigned short lt[80 * 66];
  const int bh = blockIdx.x >> 2, qt = blockIdx.x & 3;
  const int f0 = qt * 64;
  for (int e = threadIdx.x; e < 64 * 80; e += 256) {
    int fl = e / 80, d = e - fl * 80;
    float s = 0.f;
#pragma unroll
    for (int c = 0; c < NCHUNK; ++c)
      s += pkv[((size_t)(c * 64 + bh)) * NF * 80 + (size_t)(f0 + fl) * 80 + d];
    lt[d * 66 + fl] = f2bf(s);
  }
  __syncthreads();
  for (int o = threadIdx.x; o < 80 * 64; o += 256) {
    int d = o >> 6, fl = o & 63;
    kvT[(size_t)bh * 80 * NF + d * 256 + f0 + fl] = lt[d * 66 + fl];
  }
}

// ---------------------------------------------------------------------------
// attn kernel: grid (64 bh, 8), 8 x 64-row tiles per block.  R2-EXACT.
//   q' = cos(q @ rffWT^T + b)*scale; num = q' @ kvT^T; att = num/(den+eps)
// ---------------------------------------------------------------------------
__global__ __launch_bounds__(256) void attn_kernel(
    const unsigned short* __restrict__ qg, const unsigned short* __restrict__ kvTg,
    const unsigned short* __restrict__ rffWT, const float* __restrict__ rffb,
    unsigned short* __restrict__ att)
{
  __shared__ __align__(16) unsigned short qps[64 * 264];   // q' [s][f]
  __shared__ __align__(16) unsigned short kvs[80 * 264];   // kvT [d][f]
  const int bh = blockIdx.x;
  const int b = bh >> 4, h = bh & 15;
  const int tid = threadIdx.x;
  const int lane = tid & 63, wave = tid >> 6;
  const int col = lane & 15, quad = lane >> 4;
  const f4v zz = {0.f, 0.f, 0.f, 0.f};

  s8v wf[2][4];
  float bfv[4];
#pragma unroll
  for (int ks = 0; ks < 2; ++ks)
#pragma unroll
    for (int t = 0; t < 4; ++t)
      wf[ks][t] = *(const s8v*)(rffWT +
          (size_t)(wave * 64 + t * 16 + col) * 64 + ks * 32 + quad * 8);
#pragma unroll
  for (int j = 0; j < 4; ++j) bfv[j] = rffb[wave * 64 + j * 16 + col];

  // stage kv [80][256] -> kvs stride 264
  for (int c = tid; c < 2560; c += 256) {
    int d = c >> 5, ch = c & 31;
    *(s8v*)&kvs[d * 264 + ch * 8] =
        *(const s8v*)(kvTg + (size_t)bh * 80 * NF + d * 256 + ch * 8);
  }

  s8v qf[2][4];
  {
    const int s0 = blockIdx.y * 512;
#pragma unroll
    for (int ks = 0; ks < 2; ++ks)
#pragma unroll
      for (int t = 0; t < 4; ++t)
        qf[ks][t] = *(const s8v*)(qg +
            ((size_t)(b * S_LEN + s0 + t * 16 + col)) * DMODEL + h * KDIM + ks * 32 + quad * 8);
  }

  for (int it = 0; it < 8; ++it) {
    const int s0 = blockIdx.y * 512 + it * 64;
    // proj: A = preloaded q-frags, B = registers
    f4v p[4][4];
#pragma unroll
    for (int i = 0; i < 4; ++i)
#pragma unroll
      for (int j = 0; j < 4; ++j) p[i][j] = zz;
#pragma unroll
    for (int ks = 0; ks < 2; ++ks)
#pragma unroll
      for (int i = 0; i < 4; ++i)
#pragma unroll
        for (int j = 0; j < 4; ++j) p[i][j] = MFMA16(qf[ks][i], wf[ks][j], p[i][j]);
    // prefetch next tile's q-frags (drains under cos + num-MFMA)
    s8v qn[2][4];
    if (it < 7) {
      const int s1 = s0 + 64;
#pragma unroll
      for (int ks = 0; ks < 2; ++ks)
#pragma unroll
        for (int t = 0; t < 4; ++t)
          qn[ks][t] = *(const s8v*)(qg +
              ((size_t)(b * S_LEN + s1 + t * 16 + col)) * DMODEL + h * KDIM + ks * 32 + quad * 8);
    }
    __syncthreads();   // previous num-MFMA done reading qps (also fences kvs stage)
#pragma unroll
    for (int j = 0; j < 4; ++j) {
      int f = wave * 64 + j * 16 + col;
#pragma unroll
      for (int i = 0; i < 4; ++i)
#pragma unroll
        for (int r = 0; r < 4; ++r) {
          int s = i * 16 + quad * 4 + r;
          qps[s * 264 + f] = f2bf(__cosf(p[i][j][r] + bfv[j]) * RFF_SCALE);
        }
    }
    __syncthreads();
    // num: A = qps rows wave*16..+15, B = kvs, K=256
    f4v acc[5];
#pragma unroll
    for (int j = 0; j < 5; ++j) acc[j] = zz;
#pragma unroll
    for (int k0 = 0; k0 < 256; k0 += 32) {
      s8v af = *(const s8v*)&qps[(wave * 16 + col) * 264 + k0 + quad * 8];
      s8v bf[5];
#pragma unroll
      for (int t = 0; t < 5; ++t)
        bf[t] = *(const s8v*)&kvs[(t * 16 + col) * 264 + k0 + quad * 8];
#pragma unroll
      for (int j = 0; j < 5; ++j) acc[j] = MFMA16(af, bf[j], acc[j]);
    }
    float inv[4];
#pragma unroll
    for (int r = 0; r < 4; ++r) {
      float den = __shfl(acc[4][r], lane & 48);
      inv[r] = 1.0f / (den + 1e-6f);
    }
#pragma unroll
    for (int r = 0; r < 4; ++r) {
      int m = s0 + wave * 16 + quad * 4 + r;
      size_t obase = ((size_t)(b * S_LEN + m)) * DMODEL + h * KDIM;
#pragma unroll
      for (int j = 0; j < 4; ++j)
        att[obase + j * 16 + col] = f2bf(acc[j][r] * inv[r]);
    }
    if (it < 7) {
#pragma unroll
      for (int ks = 0; ks < 2; ++ks)
#pragma unroll
        for (int t = 0; t < 4; ++t) qf[ks][t] = qn[ks][t];
    }
  }
}

// ---------------------------------------------------------------------------
// kernel_launch. inputs: 0:x 1:Wq 2:bq 3:Wk 4:bk 5:Wv 6:bv 7:rff_W 8:rff_b 9:Wo 10:bo
// ---------------------------------------------------------------------------
extern "C" void kernel_launch(void* const* d_in, const int* in_sizes, int n_in,
                              void* d_out, int out_size, void* d_ws, size_t ws_size,
                              hipStream_t stream)
{
  const float* x    = (const float*)d_in[0];
  const float* Wq   = (const float*)d_in[1];
  const float* bq   = (const float*)d_in[2];
  const float* Wk   = (const float*)d_in[3];
  const float* bk   = (const float*)d_in[4];
  const float* Wv   = (const float*)d_in[5];
  const float* bv   = (const float*)d_in[6];
  const float* rffW = (const float*)d_in[7];
  const float* rffb = (const float*)d_in[8];
  const float* Wo   = (const float*)d_in[9];
  const float* bo   = (const float*)d_in[10];
  float* out = (float*)d_out;

  char* w = (char*)d_ws;
  const size_t XB = (size_t)NROWS * DMODEL * 2;     // 33,554,432
  const size_t WT = (size_t)DMODEL * DMODEL * 2;    // 2,097,152
  unsigned short* xb   = (unsigned short*)(w);
  unsigned short* WqT  = (unsigned short*)(w + XB);
  unsigned short* WkT  = (unsigned short*)(w + XB + WT);
  unsigned short* WvT  = (unsigned short*)(w + XB + 2 * WT);
  unsigned short* WoT  = (unsigned short*)(w + XB + 3 * WT);
  unsigned short* rWT  = (unsigned short*)(w + XB + 4 * WT);
  char* p = w + XB + 4 * WT + 65536;
  unsigned short* qb = (unsigned short*)(p);
  unsigned short* kb = (unsigned short*)(p + XB);
  unsigned short* vb = (unsigned short*)(p + 2 * XB);
  float* pkv         = (float*)(p + 3 * XB);
  unsigned short* kvT = (unsigned short*)(p + 3 * XB + (size_t)NCHUNK * 64 * NF * 80 * 4);
  unsigned short* att = kb;   // kb consumed before attn writes

  // single merged prep launch (cast + 4 transposes + rff)
  prep_kernel<<<12352, 256, 0, stream>>>(x, xb, Wq, WqT, Wk, WkT, Wv, WvT,
                                         Wo, WoT, rffW, rWT);

  // fused QKV: 64 m-tiles x 12 n-tiles (4 per weight matrix)
  gemm_bt_kernel<1, 1><<<768, 512, 0, stream>>>(
      xb, WqT, WkT, WvT, bq, bk, bv, qb, kb, vb, NROWS, DMODEL, DMODEL, 12);

  kv_kernel<<<dim3(64, NCHUNK), 256, 0, stream>>>(kb, vb, rWT, rffb, pkv);
  reduce_kv_kernel<<<256, 256, 0, stream>>>(pkv, kvT);
  attn_kernel<<<dim3(64, 8), 256, 0, stream>>>(qb, kvT, rWT, rffb, att);

  // out-proj: 64 m-tiles x 4 n-tiles
  gemm_bt_kernel<0, 0><<<256, 512, 0, stream>>>(
      att, WoT, nullptr, nullptr, bo, nullptr, nullptr, out, nullptr, nullptr,
      NROWS, DMODEL, DMODEL, 4);
}